// Round 9
// baseline (310.509 us; speedup 1.0000x reference)
//
#include <hip/hip_runtime.h>
#include <hip/hip_bf16.h>

#define FIN 128
#define HID 64
#define BSN 256            // nodes per bucket
#define BSHIFT 8
#define SRCBITS 20         // src fits in 20 bits (N < 1M)
#define EPB 8192           // edges per binning block

typedef __attribute__((ext_vector_type(8))) short short8;
typedef __attribute__((ext_vector_type(4))) float floatx4;

__device__ __forceinline__ float bf2f(unsigned short u) {
    union { unsigned int i; float f; } c;
    c.i = ((unsigned int)u) << 16;
    return c.f;
}

__device__ __forceinline__ float lo_f(unsigned u) {
    union { unsigned int i; float f; } c;
    c.i = u << 16;
    return c.f;
}

__device__ __forceinline__ float hi_f(unsigned u) {
    union { unsigned int i; float f; } c;
    c.i = u & 0xFFFF0000u;
    return c.f;
}

__device__ __forceinline__ unsigned short f2bf(float f) {
    union { float f; unsigned int i; } c;
    c.f = f;
    unsigned int u = c.i;
    unsigned int r = (u + 0x7FFFu + ((u >> 16) & 1u)) >> 16;   // RNE
    return (unsigned short)r;
}

// ---------------- bucket histogram (counts into bcur) ----------------------
__global__ void bin_count(const int* __restrict__ dst, int* __restrict__ bcnt,
                          int E, int B) {
    __shared__ int hist[512];
    for (int i = threadIdx.x; i < 512; i += 256) hist[i] = 0;
    __syncthreads();
    int base = blockIdx.x * EPB;
    int lim = min(base + EPB, E);
    for (int e = base + threadIdx.x; e < lim; e += 256)
        atomicAdd(&hist[dst[e] >> BSHIFT], 1);
    __syncthreads();
    for (int b = threadIdx.x; b < B; b += 256)
        if (hist[b]) atomicAdd(&bcnt[b], hist[b]);
}

// ---------------- scan bucket counts; bcnt becomes chunk cursor ------------
__global__ void scan_bkt(int* __restrict__ bcnt, int* __restrict__ bbase,
                         int E, int B) {
    __shared__ int s[1024];
    int t = threadIdx.x;
    int v = (t < B) ? bcnt[t] : 0;
    s[t] = v;
    __syncthreads();
    for (int off = 1; off < 1024; off <<= 1) {
        int a = (t >= off) ? s[t - off] : 0;
        __syncthreads();
        s[t] += a;
        __syncthreads();
    }
    if (t < B) { int ex = s[t] - v; bbase[t] = ex; bcnt[t] = ex; }
    if (t == 0) bbase[B] = E;
}

// ------- LDS counting sort per block, flush contiguous per-bucket runs -----
__global__ __launch_bounds__(256) void bin_fill(
    const int* __restrict__ src, const int* __restrict__ dst,
    int* __restrict__ bcur, unsigned* __restrict__ rec, int E, int B) {
    __shared__ int hist[512];
    __shared__ int cbase[512];
    __shared__ int lbase[512];
    __shared__ int psum[256];
    __shared__ unsigned recs[EPB];      // 32 KB
    int t = threadIdx.x;
    for (int i = t; i < 512; i += 256) hist[i] = 0;
    __syncthreads();
    int base = blockIdx.x * EPB;
    int lim = min(base + EPB, E);
    for (int e = base + t; e < lim; e += 256)
        atomicAdd(&hist[dst[e] >> BSHIFT], 1);
    __syncthreads();
    // claim global chunk per bucket
    for (int b = t; b < 512; b += 256) {
        int c = hist[b];
        cbase[b] = (c && b < B) ? atomicAdd(&bcur[b], c) : 0;
    }
    // exclusive scan of hist[0..511]: pair-sum + Hillis-Steele over 256
    int h0 = hist[2 * t], h1 = hist[2 * t + 1];
    psum[t] = h0 + h1;
    __syncthreads();
    int v = psum[t];
    for (int off = 1; off < 256; off <<= 1) {
        int a = (t >= off) ? psum[t - off] : 0;
        __syncthreads();
        psum[t] += a;
        __syncthreads();
    }
    int ex = psum[t] - v;
    lbase[2 * t] = ex;
    lbase[2 * t + 1] = ex + h0;
    hist[2 * t] = 0;                     // reuse as cursor
    hist[2 * t + 1] = 0;
    __syncthreads();
    // LDS scatter into bucket-sorted order
    for (int e = base + t; e < lim; e += 256) {
        int sv = src[e], d = dst[e];
        int b = d >> BSHIFT;
        int slot = lbase[b] + atomicAdd(&hist[b], 1);
        recs[slot] = (unsigned)sv | ((unsigned)(d & (BSN - 1)) << SRCBITS);
    }
    __syncthreads();
    // flush: wave per bucket, contiguous run to global chunk
    int wave = t >> 6, lane = t & 63;
    for (int b = wave; b < B; b += 4) {
        int c = hist[b];
        int lb = lbase[b], gb = cbase[b];
        for (int l = lane; l < c; l += 64)
            rec[gb + l] = recs[lb + l];
    }
}

// ------- per-bucket: count/scan 256 local nodes, emit row/rend/dinv/csr ----
__global__ void csr_build(const unsigned* __restrict__ rec, const int* __restrict__ bbase,
                          int* __restrict__ row, int* __restrict__ rend,
                          int* __restrict__ csr, float* __restrict__ dinv, int N) {
    __shared__ int cnt[BSN], excl[BSN], cur[BSN];
    int b = blockIdx.x, t = threadIdx.x;
    cnt[t] = 0;
    __syncthreads();
    int start = bbase[b], end = bbase[b + 1];
    for (int i = start + t; i < end; i += 256)
        atomicAdd(&cnt[rec[i] >> SRCBITS], 1);
    __syncthreads();
    excl[t] = cnt[t];
    __syncthreads();
    for (int off = 1; off < BSN; off <<= 1) {        // Hillis-Steele inclusive
        int a = (t >= off) ? excl[t - off] : 0;
        __syncthreads();
        excl[t] += a;
        __syncthreads();
    }
    {
        int inc = excl[t];
        int ex = inc - cnt[t];
        excl[t] = ex;                                // now exclusive
        cur[t] = 0;
        int n = b * BSN + t;
        if (n < N) {
            row[n]  = start + ex;
            rend[n] = start + inc;
            dinv[n] = rsqrtf((float)cnt[t] + 1.0f);
        }
    }
    __syncthreads();
    for (int i = start + t; i < end; i += 256) {     // hot 16KB region permute
        unsigned r = rec[i];
        int dl = r >> SRCBITS;
        int slot = atomicAdd(&cur[dl], 1);
        csr[start + excl[dl] + slot] = (int)(r & ((1u << SRCBITS) - 1));
    }
}

// --------- h0' = bf16((x @ W1) * dinv[n]) via MFMA, fp32->bf16 in-register --
__global__ __launch_bounds__(256) void gemm1_mfma(
    const float* __restrict__ x, const float* __restrict__ W1,
    const float* __restrict__ dinv, unsigned short* __restrict__ h0, int N) {
    int wave = threadIdx.x >> 6, lane = threadIdx.x & 63;
    int m = lane & 15, q = lane >> 4;
    short8 bfr[4][4];
#pragma unroll
    for (int ct = 0; ct < 4; ++ct)
#pragma unroll
        for (int kk = 0; kk < 4; ++kk) {
            short8 tf;
#pragma unroll
            for (int jj = 0; jj < 8; ++jj)
                tf[jj] = (short)f2bf(W1[(kk * 32 + q * 8 + jj) * HID + ct * 16 + m]);
            bfr[ct][kk] = tf;
        }
    int ntiles = N >> 4;
    for (int t = blockIdx.x * 4 + wave; t < ntiles; t += gridDim.x * 4) {
        int nbase = t << 4;
        const float* xr = x + (size_t)(nbase + m) * FIN + q * 8;
        short8 afr[4];
#pragma unroll
        for (int kk = 0; kk < 4; ++kk) {
            float4 p0 = *((const float4*)(xr + kk * 32));
            float4 p1 = *((const float4*)(xr + kk * 32 + 4));
            short8 ta;
            ta[0] = (short)f2bf(p0.x); ta[1] = (short)f2bf(p0.y);
            ta[2] = (short)f2bf(p0.z); ta[3] = (short)f2bf(p0.w);
            ta[4] = (short)f2bf(p1.x); ta[5] = (short)f2bf(p1.y);
            ta[6] = (short)f2bf(p1.z); ta[7] = (short)f2bf(p1.w);
            afr[kk] = ta;
        }
        floatx4 cacc[4];
#pragma unroll
        for (int ct = 0; ct < 4; ++ct) cacc[ct] = floatx4{0.f, 0.f, 0.f, 0.f};
#pragma unroll
        for (int ct = 0; ct < 4; ++ct)
#pragma unroll
            for (int kk = 0; kk < 4; ++kk)
                cacc[ct] = __builtin_amdgcn_mfma_f32_16x16x32_bf16(afr[kk], bfr[ct][kk], cacc[ct], 0, 0, 0);
        float4 dv = *((const float4*)(dinv + nbase + q * 4));
#pragma unroll
        for (int ct = 0; ct < 4; ++ct) {
#pragma unroll
            for (int r = 0; r < 4; ++r) {
                float d = (r == 0) ? dv.x : (r == 1) ? dv.y : (r == 2) ? dv.z : dv.w;
                int n = nbase + q * 4 + r;
                h0[(size_t)n * HID + ct * 16 + m] = f2bf(cacc[ct][r] * d);
            }
        }
    }
}

// ---- pull: wave per dst node (grid-stride). Lanes 0-31 even edges, 32-63 odd;
// each lane loads a packed uint (2 bf16) -> one vmem = TWO full 128 B rows.
// 8 unrolled loads = 16 lines in flight. Scalar (wave-uniform) csr indices.
// mode 0: outp = bf16(relu(di*(acc+self) + b1[f]) * di)   (-> h')
// mode 1: outp = bf16(di*(acc+self))                      (-> abar)
__global__ __launch_bounds__(256) void pull(
    const unsigned short* __restrict__ hp, const int* __restrict__ row,
    const int* __restrict__ rend, const int* __restrict__ csr,
    const float* __restrict__ dinv, const float* __restrict__ b1,
    unsigned short* __restrict__ outp, int N, int mode) {
    const unsigned* hp32 = (const unsigned*)hp;
    unsigned* out32 = (unsigned*)outp;
    int wave = threadIdx.x >> 6, lane = threadIdx.x & 63;
    int half = lane >> 5, f2 = lane & 31;
    float bx = b1[2 * f2], by = b1[2 * f2 + 1];
    int gw = blockIdx.x * 4 + wave, nw = gridDim.x * 4;
    for (int n = gw; n < N; n += nw) {
        int start = __builtin_amdgcn_readfirstlane(row[n]);
        int end   = __builtin_amdgcn_readfirstlane(rend[n]);
        float ax[8], ay[8];
#pragma unroll
        for (int i = 0; i < 8; ++i) { ax[i] = 0.f; ay[i] = 0.f; }
        int j = start;
        for (; j + 16 <= end; j += 16) {
            unsigned u[8];
#pragma unroll
            for (int i = 0; i < 8; ++i) {
                int s0 = __builtin_amdgcn_readfirstlane(csr[j + 2 * i]);
                int s1 = __builtin_amdgcn_readfirstlane(csr[j + 2 * i + 1]);
                int s = half ? s1 : s0;
                u[i] = hp32[(size_t)s * 32 + f2];
            }
#pragma unroll
            for (int i = 0; i < 8; ++i) {
                ax[i] += lo_f(u[i]);
                ay[i] += hi_f(u[i]);
            }
        }
        for (; j + 2 <= end; j += 2) {
            int s0 = __builtin_amdgcn_readfirstlane(csr[j]);
            int s1 = __builtin_amdgcn_readfirstlane(csr[j + 1]);
            int s = half ? s1 : s0;
            unsigned u = hp32[(size_t)s * 32 + f2];
            ax[0] += lo_f(u); ay[0] += hi_f(u);
        }
        if (j < end) {
            int s = __builtin_amdgcn_readfirstlane(csr[j]);
            unsigned u = hp32[(size_t)s * 32 + f2];
            ax[1] += half ? 0.f : lo_f(u);
            ay[1] += half ? 0.f : hi_f(u);
        }
        float sx = ((ax[0] + ax[1]) + (ax[2] + ax[3])) + ((ax[4] + ax[5]) + (ax[6] + ax[7]));
        float sy = ((ay[0] + ay[1]) + (ay[2] + ay[3])) + ((ay[4] + ay[5]) + (ay[6] + ay[7]));
        sx += __shfl_xor(sx, 32);
        sy += __shfl_xor(sy, 32);
        unsigned us = hp32[(size_t)n * 32 + f2];
        sx += lo_f(us); sy += hi_f(us);
        float di = dinv[n];
        if (half == 0) {
            float vx, vy;
            if (mode == 0) {
                vx = di * sx + bx;
                vy = di * sy + by;
                vx = (vx > 0.f ? vx : 0.f) * di;
                vy = (vy > 0.f ? vy : 0.f) * di;
            } else {
                vx = di * sx;
                vy = di * sy;
            }
            out32[(size_t)n * 32 + f2] = (unsigned)f2bf(vx) | ((unsigned)f2bf(vy) << 16);
        }
    }
}

// ---------------- out = abar @ [Wmu|Wls] + [bmu|bls] via MFMA ---------------
__global__ __launch_bounds__(256, 4) void gemm2_mfma(
    const unsigned short* __restrict__ abar,
    const float* __restrict__ Wmu, const float* __restrict__ bmu,
    const float* __restrict__ Wls, const float* __restrict__ bls,
    float* __restrict__ out, int N) {
    int wave = threadIdx.x >> 6, lane = threadIdx.x & 63;
    int m = lane & 15, q = lane >> 4;
    short8 bfr[4][2];
#pragma unroll
    for (int ct = 0; ct < 4; ++ct)
#pragma unroll
        for (int kk = 0; kk < 2; ++kk) {
            short8 tf;
#pragma unroll
            for (int jj = 0; jj < 8; ++jj) {
                int k = kk * 32 + q * 8 + jj;
                int col = ct * 16 + m;
                float w = (col < 32) ? Wmu[k * 32 + col] : Wls[k * 32 + (col - 32)];
                tf[jj] = (short)f2bf(w);
            }
            bfr[ct][kk] = tf;
        }
    float bias[4];
#pragma unroll
    for (int ct = 0; ct < 4; ++ct) {
        int col = ct * 16 + m;
        bias[ct] = (col < 32) ? bmu[col] : bls[col - 32];
    }
    int ntiles = N >> 4;
    int gw = blockIdx.x * 4 + wave;
    int nw = gridDim.x * 4;
    for (int t = gw; t < ntiles; t += nw) {
        int nbase = t << 4;
        const unsigned short* arow = abar + (size_t)(nbase + m) * HID;
        short8 a0 = *((const short8*)(arow + q * 8));
        short8 a1 = *((const short8*)(arow + 32 + q * 8));
        floatx4 cacc[4];
#pragma unroll
        for (int ct = 0; ct < 4; ++ct) cacc[ct] = floatx4{0.f, 0.f, 0.f, 0.f};
#pragma unroll
        for (int ct = 0; ct < 4; ++ct) {
            cacc[ct] = __builtin_amdgcn_mfma_f32_16x16x32_bf16(a0, bfr[ct][0], cacc[ct], 0, 0, 0);
            cacc[ct] = __builtin_amdgcn_mfma_f32_16x16x32_bf16(a1, bfr[ct][1], cacc[ct], 0, 0, 0);
        }
#pragma unroll
        for (int ct = 0; ct < 4; ++ct) {
            int col = ct * 16 + m;
            int which = col >> 5, o = col & 31;
#pragma unroll
            for (int r = 0; r < 4; ++r) {
                int n = nbase + q * 4 + r;
                out[(size_t)which * N * 32 + (size_t)n * 32 + o] = cacc[ct][r] + bias[ct];
            }
        }
    }
}

// ---------------------------------------------------------------------------
extern "C" void kernel_launch(void* const* d_in, const int* in_sizes, int n_in,
                              void* d_out, int out_size, void* d_ws, size_t ws_size,
                              hipStream_t stream) {
    const float* x   = (const float*)d_in[0];
    const int*   ei  = (const int*)d_in[1];
    const float* W1  = (const float*)d_in[2];
    const float* b1  = (const float*)d_in[3];
    const float* Wmu = (const float*)d_in[4];
    const float* bmu = (const float*)d_in[5];
    const float* Wls = (const float*)d_in[6];
    const float* bls = (const float*)d_in[7];
    int N = in_sizes[0] / FIN;
    int E = in_sizes[1] / 2;
    const int* src = ei;
    const int* dst = ei + E;
    float* out = (float*)d_out;

    int B = (N + BSN - 1) / BSN;            // 391 buckets
    int nbin = (E + EPB - 1) / EPB;         // 196 binning blocks

    // ws layout (4-byte units):
    // dinv[N] | row[N] | rend[N] | bbase[B+1] | bcur[B] | csr[E] |
    // bufA[N*64 bf16] | region2[max(E*4, N*128) bytes] (rec during build, then bufB)
    float* dinv  = (float*)d_ws;
    int*   row   = (int*)(dinv + N);
    int*   rend  = row + N;
    int*   bbase = rend + N;
    int*   bcur  = bbase + (B + 1);
    int*   csr   = bcur + B;
    unsigned short* bufA = (unsigned short*)(csr + E);          // h0' / abar
    char* region2 = (char*)(bufA + (size_t)N * HID);
    unsigned* rec        = (unsigned*)region2;                  // dead after csr_build
    unsigned short* bufB = (unsigned short*)region2;            // h'

    hipMemsetAsync(bcur, 0, (size_t)B * sizeof(int), stream);
    bin_count<<<nbin, 256, 0, stream>>>(dst, bcur, E, B);
    scan_bkt<<<1, 1024, 0, stream>>>(bcur, bbase, E, B);
    bin_fill<<<nbin, 256, 0, stream>>>(src, dst, bcur, rec, E, B);
    csr_build<<<B, 256, 0, stream>>>(rec, bbase, row, rend, csr, dinv, N);

    gemm1_mfma<<<256, 256, 0, stream>>>(x, W1, dinv, bufA, N);

    pull<<<2048, 256, 0, stream>>>(bufA, row, rend, csr, dinv, b1, bufB, N, 0);
    pull<<<2048, 256, 0, stream>>>(bufB, row, rend, csr, dinv, b1, bufA, N, 1);

    gemm2_mfma<<<256, 256, 0, stream>>>(bufA, Wmu, bmu, Wls, bls, out, N);
}